// Round 13
// baseline (576.675 us; speedup 1.0000x reference)
//
#include <hip/hip_runtime.h>

#define NN   4096   // nodes
#define ED   64     // embed dim
#define DIN  256    // in_dim
#define DOUT 256    // out_dim
#define NB   32     // batch

typedef __attribute__((ext_vector_type(8))) short bf16x8;
typedef __attribute__((ext_vector_type(4))) float f32x4;

__device__ __forceinline__ unsigned short f2bf(float f) {
    union { float f; unsigned u; } v; v.f = f;
    unsigned r = v.u + 0x7FFF + ((v.u >> 16) & 1);   // round-to-nearest-even
    return (unsigned short)(r >> 16);
}
__device__ __forceinline__ float bf2f(unsigned short s) {
    union { unsigned u; float f; } v; v.u = ((unsigned)s) << 16;
    return v.f;
}

// async global->LDS, 16B per lane; lds dst must be wave-uniform (lane*16 implicit)
#define GLDS16(g, l) __builtin_amdgcn_global_load_lds( \
    (const __attribute__((address_space(1))) void*)(g), \
    (__attribute__((address_space(3))) void*)(l), 16, 0, 0)

__device__ __forceinline__ void fma4(float4& d, float s, const float4& v) {
    d.x = fmaf(s, v.x, d.x);
    d.y = fmaf(s, v.y, d.y);
    d.z = fmaf(s, v.z, d.z);
    d.w = fmaf(s, v.w, d.w);
}

// ---------------- K1: E = emb_table[node_ids] (f32) ----------------
__global__ void k_gather(const float* __restrict__ emb, const int* __restrict__ ids,
                         float* __restrict__ E) {
    int n = blockIdx.x;
    int e = threadIdx.x;          // 64 threads
    int id = ids[n];
    id = id < 0 ? 0 : (id >= NN ? NN - 1 : id);
    E[(size_t)n * ED + e] = emb[(size_t)id * ED + e];
}

// ---------------- K2a: logits = relu(E E^T) -> bf16 ----------------
__global__ __launch_bounds__(256) void k_logits(const float* __restrict__ E,
                                                unsigned short* __restrict__ adjbf) {
    __shared__ __align__(16) float Ea[ED][64 + 4];   // transposed: Ea[k][row]
    __shared__ __align__(16) float Eb[ED][64 + 4];
    const int tid = threadIdx.x;
    const int ty = tid >> 4, tx = tid & 15;
    const int rb = blockIdx.x, cb = blockIdx.y;

    #pragma unroll
    for (int k = 0; k < 4; ++k) {
        int l = tid + k * 256;
        int row = l >> 4;
        int kq = (l & 15) * 4;
        float4 va = *(const float4*)&E[(size_t)(rb * 64 + row) * ED + kq];
        Ea[kq + 0][row] = va.x; Ea[kq + 1][row] = va.y;
        Ea[kq + 2][row] = va.z; Ea[kq + 3][row] = va.w;
        float4 vb = *(const float4*)&E[(size_t)(cb * 64 + row) * ED + kq];
        Eb[kq + 0][row] = vb.x; Eb[kq + 1][row] = vb.y;
        Eb[kq + 2][row] = vb.z; Eb[kq + 3][row] = vb.w;
    }
    __syncthreads();

    float4 acc[4] = {};
    #pragma unroll
    for (int k = 0; k < ED; ++k) {
        float4 ar = *(const float4*)&Ea[k][ty * 4];
        float4 br = *(const float4*)&Eb[k][tx * 4];
        fma4(acc[0], ar.x, br);
        fma4(acc[1], ar.y, br);
        fma4(acc[2], ar.z, br);
        fma4(acc[3], ar.w, br);
    }

    #pragma unroll
    for (int i = 0; i < 4; ++i) {
        float4 v = acc[i];
        ushort4 s;
        s.x = f2bf(fmaxf(v.x, 0.f)); s.y = f2bf(fmaxf(v.y, 0.f));
        s.z = f2bf(fmaxf(v.z, 0.f)); s.w = f2bf(fmaxf(v.w, 0.f));
        size_t n = (size_t)(rb * 64 + ty * 4 + i);
        *(ushort4*)&adjbf[n * NN + cb * 64 + tx * 4] = s;
    }
}

// ---------------- K2b: row softmax, bf16 in-place (single pass/row) ----------------
__global__ __launch_bounds__(256) void k_softmax(unsigned short* __restrict__ adj) {
    __shared__ float red[256];
    const int tid = threadIdx.x;
    const size_t base = (size_t)blockIdx.x * NN + (size_t)tid * 16;

    unsigned short t16[16];
    *(uint4*)&t16[0] = *(const uint4*)&adj[base];
    *(uint4*)&t16[8] = *(const uint4*)&adj[base + 8];
    float v[16];
    float mx = 0.0f;                      // relu >= 0
    #pragma unroll
    for (int j = 0; j < 16; ++j) { v[j] = bf2f(t16[j]); mx = fmaxf(mx, v[j]); }

    red[tid] = mx; __syncthreads();
    for (int off = 128; off > 0; off >>= 1) {
        if (tid < off) red[tid] = fmaxf(red[tid], red[tid + off]);
        __syncthreads();
    }
    mx = red[0];
    __syncthreads();

    float s = 0.f;
    #pragma unroll
    for (int j = 0; j < 16; ++j) { v[j] = expf(v[j] - mx); s += v[j]; }
    red[tid] = s; __syncthreads();
    for (int off = 128; off > 0; off >>= 1) {
        if (tid < off) red[tid] += red[tid + off];
        __syncthreads();
    }
    const float inv = 1.0f / red[0];

    #pragma unroll
    for (int j = 0; j < 16; ++j) t16[j] = f2bf(v[j] * inv);
    *(uint4*)&adj[base]     = *(const uint4*)&t16[0];
    *(uint4*)&adj[base + 8] = *(const uint4*)&t16[8];
}

// ---------------- K3: WT[m][k] = bf16(W[k][m]) ----------------
__global__ void k_wt(const float* __restrict__ W, unsigned short* __restrict__ WT) {
    int m = blockIdx.x;    // dout
    int k = threadIdx.x;   // din
    WT[(size_t)m * DIN + k] = f2bf(W[(size_t)k * DOUT + m]);
}

// ---------------- K4: yT[b][dout][node] = bf16( (x@W)^T ) ----------------
__global__ __launch_bounds__(256) void k_y(const unsigned short* __restrict__ WT,
                                           const float* __restrict__ x,
                                           unsigned short* __restrict__ yT) {
    __shared__ __align__(16) short As[128 * 32];
    __shared__ __align__(16) short Bs[128 * 32];
    const int tid = threadIdx.x;
    const int lane = tid & 63, w = tid >> 6;
    const int wr = (w >> 1) * 64, wc = (w & 1) * 64;
    const int fr = lane & 15, fq = lane >> 4;
    const int m0 = blockIdx.x * 128;   // dout tile
    const int n0 = blockIdx.y * 128;   // node tile
    const int b  = blockIdx.z;
    const float* xb = x + (size_t)b * NN * DIN;
    const int brow = tid >> 1, bh = (tid & 1) * 16;   // B staging: row, k-half

    f32x4 acc[4][4];
    #pragma unroll
    for (int i = 0; i < 4; ++i)
        #pragma unroll
        for (int j = 0; j < 4; ++j) acc[i][j] = (f32x4){0.f, 0.f, 0.f, 0.f};

    for (int k0 = 0; k0 < DIN; k0 += 32) {
        __syncthreads();
        #pragma unroll
        for (int i = 0; i < 2; ++i) {
            int idx = (w * 2 + i) * 512 + lane * 8;
            int row = idx >> 5, kk = idx & 31;
            GLDS16(WT + (size_t)(m0 + row) * DIN + k0 + kk, &As[(w * 2 + i) * 512]);
        }
        float fv[16];
        *(float4*)&fv[0]  = *(const float4*)&xb[(size_t)(n0 + brow) * DIN + k0 + bh + 0];
        *(float4*)&fv[4]  = *(const float4*)&xb[(size_t)(n0 + brow) * DIN + k0 + bh + 4];
        *(float4*)&fv[8]  = *(const float4*)&xb[(size_t)(n0 + brow) * DIN + k0 + bh + 8];
        *(float4*)&fv[12] = *(const float4*)&xb[(size_t)(n0 + brow) * DIN + k0 + bh + 12];
        unsigned u[8];
        #pragma unroll
        for (int j = 0; j < 8; ++j)
            u[j] = (unsigned)f2bf(fv[2 * j]) | ((unsigned)f2bf(fv[2 * j + 1]) << 16);
        *(uint4*)&Bs[brow * 32 + bh]     = make_uint4(u[0], u[1], u[2], u[3]);
        *(uint4*)&Bs[brow * 32 + bh + 8] = make_uint4(u[4], u[5], u[6], u[7]);
        __syncthreads();

        bf16x8 a[4], bb[4];
        #pragma unroll
        for (int mi = 0; mi < 4; ++mi)
            a[mi] = *(const bf16x8*)&As[(wr + mi * 16 + fr) * 32 + fq * 8];
        #pragma unroll
        for (int ni = 0; ni < 4; ++ni)
            bb[ni] = *(const bf16x8*)&Bs[(wc + ni * 16 + fr) * 32 + fq * 8];
        #pragma unroll
        for (int mi = 0; mi < 4; ++mi)
            #pragma unroll
            for (int ni = 0; ni < 4; ++ni)
                acc[mi][ni] = __builtin_amdgcn_mfma_f32_16x16x32_bf16(
                    a[mi], bb[ni], acc[mi][ni], 0, 0, 0);
    }

    unsigned short* yb = yT + (size_t)b * DOUT * NN;
    #pragma unroll
    for (int mi = 0; mi < 4; ++mi)
        #pragma unroll
        for (int ni = 0; ni < 4; ++ni)
            #pragma unroll
            for (int r = 0; r < 4; ++r) {
                int row = m0 + wr + mi * 16 + fq * 4 + r;   // dout
                int col = n0 + wc + ni * 16 + fr;           // node
                yb[(size_t)row * NN + col] = f2bf(acc[mi][ni][r]);
            }
}

// ---------------- K5: big GEMM, 256x128 tile, A-in-LDS(frag-order) + B-direct-to-reg ----
// C[4096 x 8192] = adj[4096 x 4096] @ Y[4096 x 8192], Y^T = yT flat [8192][4096].
// 4 waves (2M x 2N), wave tile 128x64. A staged via global_load_lds in FRAGMENT
// ORDER (each 16-row x K32 frag = contiguous 1KB chunk; ds_read at chunk+lane*16,
// conflict-free by construction). B frags loaded global->VGPR (L2-resident slab),
// double-buffered by parity. 3-buffer A ring (48KB LDS), 1 barrier + vmcnt(4)/tile.
// grid (16, 64): bx = m-tile (node), ny = 128-col slab of Y.
__global__ __launch_bounds__(256, 2) void k_gcn(const unsigned short* __restrict__ adj,
                                                const unsigned short* __restrict__ yT,
                                                const float* __restrict__ bias,
                                                float* __restrict__ out) {
    __shared__ __align__(16) char smem[49152];    // 3 x 16KB A buffers

    const int tid  = threadIdx.x;
    const int lane = tid & 63, wid = tid >> 6;    // 4 waves
    const int fr = lane & 15, fq = lane >> 4;
    const int wr = wid >> 1, wc = wid & 1;        // 2 M-waves x 2 N-waves (128x64/wave)
    const int m0 = blockIdx.x * 256;              // node tile base
    const int ny = blockIdx.y;                    // 128-wide column slab of Y

    const char* Apanel = (const char*)(adj + (size_t)m0 * NN);          // row stride 8192 B
    const char* Bpanel = (const char*)(yT + (size_t)ny * 128 * NN);     // 128 rows

    // per-lane global source bases.
    // A chunk c = wid*4+i holds rows c*16..c*16+15, lane l -> row c*16+(l&15),
    // k-octet (l>>4)*16B.  LDS dest = buf + c*1024 (+ lane*16 implicit).
    const char* asrc[4];
    #pragma unroll
    for (int i = 0; i < 4; ++i)
        asrc[i] = Apanel + (size_t)((wid * 4 + i) * 16 + fr) * 8192 + fq * 16;
    // B frag ni: lane l -> col wc*64+ni*16+(l&15), k-octet (l>>4)*16B
    const char* bsrc[4];
    #pragma unroll
    for (int ni = 0; ni < 4; ++ni)
        bsrc[ni] = Bpanel + (size_t)(wc * 64 + ni * 16 + fr) * 8192 + fq * 16;

    #define STAGE_A(T, buf)                                                      \
        { _Pragma("unroll")                                                      \
          for (int i = 0; i < 4; ++i)                                            \
              GLDS16(asrc[i] + (T) * 64, (buf) + (wid * 4 + i) * 1024); }
    #define LOAD_B(T, dst)                                                       \
        { _Pragma("unroll")                                                      \
          for (int ni = 0; ni < 4; ++ni)                                         \
              asm volatile("global_load_dwordx4 %0, %1, off"                     \
                           : "=v"(dst[ni]) : "v"(bsrc[ni] + (T) * 64) : "memory"); }

    char* pA = smem;            // holds tile t
    char* pB = smem + 16384;    // holds tile t+1
    char* pC = smem + 32768;    // stage target for tile t+2

    bf16x8 Be[4], Bo[4];

    // prologue: FIFO = [A(0), B(0), A(1)]
    STAGE_A(0, pA);
    LOAD_B(0, Be);
    STAGE_A(1, pB);

    f32x4 acc[8][4];
    #pragma unroll
    for (int i = 0; i < 8; ++i)
        #pragma unroll
        for (int j = 0; j < 4; ++j) acc[i][j] = (f32x4){0.f, 0.f, 0.f, 0.f};

    #define TILE(T, Bcur, Bnxt)                                                  \
      { if ((T) < 127) { asm volatile("s_waitcnt vmcnt(4)" ::: "memory"); }      \
        else           { asm volatile("s_waitcnt vmcnt(0)" ::: "memory"); }      \
        __builtin_amdgcn_sched_barrier(0);                                       \
        asm volatile("s_barrier" ::: "memory");                                  \
        __builtin_amdgcn_sched_barrier(0);                                       \
        bf16x8 Af[8];                                                            \
        _Pragma("unroll")                                                        \
        for (int mi = 0; mi < 8; ++mi)                                           \
            Af[mi] = *(const bf16x8*)(pA + (wr * 8 + mi) * 1024 + lane * 16);    \
        if ((T) + 1 < 128) LOAD_B((T) + 1, Bnxt);                                \
        if ((T) + 2 < 128) STAGE_A((T) + 2, pC);                                 \
        __builtin_amdgcn_s_setprio(1);                                           \
        _Pragma("unroll")                                                        \
        for (int mi = 0; mi < 4; ++mi)                                           \
            _Pragma("unroll")                                                    \
            for (int ni = 0; ni < 4; ++ni)                                       \
                acc[mi][ni] = __builtin_amdgcn_mfma_f32_16x16x32_bf16(           \
                    Af[mi], Bcur[ni], acc[mi][ni], 0, 0, 0);                     \
        _Pragma("unroll")                                                        \
        for (int mi = 4; mi < 8; ++mi)                                           \
            _Pragma("unroll")                                                    \
            for (int ni = 0; ni < 4; ++ni)                                       \
                acc[mi][ni] = __builtin_amdgcn_mfma_f32_16x16x32_bf16(           \
                    Af[mi], Bcur[ni], acc[mi][ni], 0, 0, 0);                     \
        __builtin_amdgcn_s_setprio(0);                                           \
        { char* t_ = pA; pA = pB; pB = pC; pC = t_; } }

    for (int tp = 0; tp < 64; ++tp) {
        TILE(tp * 2,     Be, Bo)
        TILE(tp * 2 + 1, Bo, Be)
    }

    // ---- epilogue: bias + relu, scatter to out[b][node][dout]
    const int by = ny >> 1;
    const int dbase = (ny & 1) * 128;
    float bv[4];
    #pragma unroll
    for (int ni = 0; ni < 4; ++ni) bv[ni] = bias[dbase + wc * 64 + ni * 16 + fr];

    #pragma unroll
    for (int am = 0; am < 8; ++am) {
        const int node = m0 + wr * 128 + am * 16 + fq * 4;
        #pragma unroll
        for (int ni = 0; ni < 4; ++ni) {
            const int dcol = dbase + wc * 64 + ni * 16 + fr;
            #pragma unroll
            for (int rr = 0; rr < 4; ++rr) {
                float vv = acc[am][ni][rr] + bv[ni];
                out[((size_t)by * NN + node + rr) * DOUT + dcol] = fmaxf(vv, 0.f);
            }
        }
    }
    #undef STAGE_A
    #undef LOAD_B
    #undef TILE
}

extern "C" void kernel_launch(void* const* d_in, const int* in_sizes, int n_in,
                              void* d_out, int out_size, void* d_ws, size_t ws_size,
                              hipStream_t stream) {
    const float* x    = (const float*)d_in[0];
    const int*   ids  = (const int*)d_in[1];
    const float* emb  = (const float*)d_in[2];
    const float* W    = (const float*)d_in[3];
    const float* bias = (const float*)d_in[4];
    float* out = (float*)d_out;

    // workspace layout (97.1 MiB total)
    char* ws = (char*)d_ws;
    unsigned short* adjbf = (unsigned short*)ws;                          // 32 MiB
    float*          E     = (float*)(ws + 33554432);                      // 1 MiB
    unsigned short* WT    = (unsigned short*)(ws + 33554432 + 1048576);   // 128 KiB
    unsigned short* yT    = (unsigned short*)(ws + 33554432 + 1048576 + 131072); // 64 MiB

    k_gather  <<<NN, ED, 0, stream>>>(emb, ids, E);
    k_logits  <<<dim3(NN / 64, NN / 64), 256, 0, stream>>>(E, adjbf);
    k_softmax <<<NN, 256, 0, stream>>>(adjbf);
    k_wt      <<<DOUT, DIN, 0, stream>>>(W, WT);
    k_y       <<<dim3(DOUT / 128, NN / 128, NB), 256, 0, stream>>>(WT, x, yT);
    k_gcn     <<<dim3(16, 64), 256, 0, stream>>>(adjbf, yT, bias, out);
}

// Round 15
// 321.461 us; speedup vs baseline: 1.7939x; 1.7939x over previous
//
#include <hip/hip_runtime.h>

#define NN   4096   // nodes
#define ED   64     // embed dim
#define DIN  256    // in_dim
#define DOUT 256    // out_dim
#define NB   32     // batch

typedef __attribute__((ext_vector_type(8))) short bf16x8;
typedef __attribute__((ext_vector_type(4))) float f32x4;

__device__ __forceinline__ unsigned short f2bf(float f) {
    union { float f; unsigned u; } v; v.f = f;
    unsigned r = v.u + 0x7FFF + ((v.u >> 16) & 1);   // round-to-nearest-even
    return (unsigned short)(r >> 16);
}
__device__ __forceinline__ float bf2f(unsigned short s) {
    union { unsigned u; float f; } v; v.u = ((unsigned)s) << 16;
    return v.f;
}

// async global->LDS, 16B per lane; lds dst must be wave-uniform (lane*16 implicit)
#define GLDS16(g, l) __builtin_amdgcn_global_load_lds( \
    (const __attribute__((address_space(1))) void*)(g), \
    (__attribute__((address_space(3))) void*)(l), 16, 0, 0)

__device__ __forceinline__ void fma4(float4& d, float s, const float4& v) {
    d.x = fmaf(s, v.x, d.x);
    d.y = fmaf(s, v.y, d.y);
    d.z = fmaf(s, v.z, d.z);
    d.w = fmaf(s, v.w, d.w);
}

// ---------------- K1: Ebf = bf16(emb[node_ids]); Z = 0 ----------------
__global__ void k_gather(const float* __restrict__ emb, const int* __restrict__ ids,
                         unsigned short* __restrict__ Ebf, float* __restrict__ Z) {
    int n = blockIdx.x;
    int e = threadIdx.x;          // 64 threads
    int id = ids[n];
    id = id < 0 ? 0 : (id >= NN ? NN - 1 : id);
    Ebf[(size_t)n * ED + e] = f2bf(emb[(size_t)id * ED + e]);
    if (e == 0) Z[n] = 0.0f;      // zero row-sum accumulator every launch
}

// ---------------- K2: P = exp(relu(E E^T)) -> bf16; Z[row] += row-sums ----------------
// (softmax eliminated: logits <= ~1.5 so exp never overflows; normalization is
//  deferred to k_gcn's epilogue as acc * (1/Z[row]).)
__global__ __launch_bounds__(256) void k_logits(const unsigned short* __restrict__ Ebf,
                                                unsigned short* __restrict__ P,
                                                float* __restrict__ Z) {
    __shared__ __align__(16) float Ea[ED][64 + 4];   // transposed: Ea[k][row]
    __shared__ __align__(16) float Eb[ED][64 + 4];
    const int tid = threadIdx.x;
    const int ty = tid >> 4, tx = tid & 15;
    const int rb = blockIdx.x, cb = blockIdx.y;

    #pragma unroll
    for (int k = 0; k < 4; ++k) {
        int l = tid + k * 256;
        int row = l >> 4;
        int kq = (l & 15) * 4;
        ushort4 va = *(const ushort4*)&Ebf[(size_t)(rb * 64 + row) * ED + kq];
        Ea[kq + 0][row] = bf2f(va.x); Ea[kq + 1][row] = bf2f(va.y);
        Ea[kq + 2][row] = bf2f(va.z); Ea[kq + 3][row] = bf2f(va.w);
        ushort4 vb = *(const ushort4*)&Ebf[(size_t)(cb * 64 + row) * ED + kq];
        Eb[kq + 0][row] = bf2f(vb.x); Eb[kq + 1][row] = bf2f(vb.y);
        Eb[kq + 2][row] = bf2f(vb.z); Eb[kq + 3][row] = bf2f(vb.w);
    }
    __syncthreads();

    float4 acc[4] = {};                 // rows ty*4+i, cols tx*4..+3
    #pragma unroll
    for (int k = 0; k < ED; ++k) {
        float4 ar = *(const float4*)&Ea[k][ty * 4];
        float4 br = *(const float4*)&Eb[k][tx * 4];
        fma4(acc[0], ar.x, br);
        fma4(acc[1], ar.y, br);
        fma4(acc[2], ar.z, br);
        fma4(acc[3], ar.w, br);
    }

    float rsum[4];
    #pragma unroll
    for (int i = 0; i < 4; ++i) {
        float4 v = acc[i];
        v.x = __expf(fmaxf(v.x, 0.f)); v.y = __expf(fmaxf(v.y, 0.f));
        v.z = __expf(fmaxf(v.z, 0.f)); v.w = __expf(fmaxf(v.w, 0.f));
        rsum[i] = v.x + v.y + v.z + v.w;
        ushort4 s;
        s.x = f2bf(v.x); s.y = f2bf(v.y); s.z = f2bf(v.z); s.w = f2bf(v.w);
        size_t n = (size_t)(rb * 64 + ty * 4 + i);
        *(ushort4*)&P[n * NN + cb * 64 + tx * 4] = s;
    }
    // reduce across tx (16 lanes within the wave's quarter) then one atomic/row
    #pragma unroll
    for (int i = 0; i < 4; ++i) {
        #pragma unroll
        for (int off = 1; off < 16; off <<= 1)
            rsum[i] += __shfl_xor(rsum[i], off);
        if (tx == 0) atomicAdd(&Z[rb * 64 + ty * 4 + i], rsum[i]);
    }
}

// ---------------- K3: WT[m][k] = bf16(W[k][m]) ----------------
__global__ void k_wt(const float* __restrict__ W, unsigned short* __restrict__ WT) {
    int m = blockIdx.x;    // dout
    int k = threadIdx.x;   // din
    WT[(size_t)m * DIN + k] = f2bf(W[(size_t)k * DOUT + m]);
}

// ---------------- K4: yT[b][dout][node] = bf16( (x@W)^T ) ----------------
__global__ __launch_bounds__(256) void k_y(const unsigned short* __restrict__ WT,
                                           const float* __restrict__ x,
                                           unsigned short* __restrict__ yT) {
    __shared__ __align__(16) short As[128 * 32];
    __shared__ __align__(16) short Bs[128 * 32];
    const int tid = threadIdx.x;
    const int lane = tid & 63, w = tid >> 6;
    const int wr = (w >> 1) * 64, wc = (w & 1) * 64;
    const int fr = lane & 15, fq = lane >> 4;
    const int m0 = blockIdx.x * 128;   // dout tile
    const int n0 = blockIdx.y * 128;   // node tile
    const int b  = blockIdx.z;
    const float* xb = x + (size_t)b * NN * DIN;
    const int brow = tid >> 1, bh = (tid & 1) * 16;   // B staging: row, k-half

    f32x4 acc[4][4];
    #pragma unroll
    for (int i = 0; i < 4; ++i)
        #pragma unroll
        for (int j = 0; j < 4; ++j) acc[i][j] = (f32x4){0.f, 0.f, 0.f, 0.f};

    for (int k0 = 0; k0 < DIN; k0 += 32) {
        __syncthreads();
        #pragma unroll
        for (int i = 0; i < 2; ++i) {
            int idx = (w * 2 + i) * 512 + lane * 8;
            int row = idx >> 5, kk = idx & 31;
            GLDS16(WT + (size_t)(m0 + row) * DIN + k0 + kk, &As[(w * 2 + i) * 512]);
        }
        float fv[16];
        *(float4*)&fv[0]  = *(const float4*)&xb[(size_t)(n0 + brow) * DIN + k0 + bh + 0];
        *(float4*)&fv[4]  = *(const float4*)&xb[(size_t)(n0 + brow) * DIN + k0 + bh + 4];
        *(float4*)&fv[8]  = *(const float4*)&xb[(size_t)(n0 + brow) * DIN + k0 + bh + 8];
        *(float4*)&fv[12] = *(const float4*)&xb[(size_t)(n0 + brow) * DIN + k0 + bh + 12];
        unsigned u[8];
        #pragma unroll
        for (int j = 0; j < 8; ++j)
            u[j] = (unsigned)f2bf(fv[2 * j]) | ((unsigned)f2bf(fv[2 * j + 1]) << 16);
        *(uint4*)&Bs[brow * 32 + bh]     = make_uint4(u[0], u[1], u[2], u[3]);
        *(uint4*)&Bs[brow * 32 + bh + 8] = make_uint4(u[4], u[5], u[6], u[7]);
        __syncthreads();

        bf16x8 a[4], bb[4];
        #pragma unroll
        for (int mi = 0; mi < 4; ++mi)
            a[mi] = *(const bf16x8*)&As[(wr + mi * 16 + fr) * 32 + fq * 8];
        #pragma unroll
        for (int ni = 0; ni < 4; ++ni)
            bb[ni] = *(const bf16x8*)&Bs[(wc + ni * 16 + fr) * 32 + fq * 8];
        #pragma unroll
        for (int mi = 0; mi < 4; ++mi)
            #pragma unroll
            for (int ni = 0; ni < 4; ++ni)
                acc[mi][ni] = __builtin_amdgcn_mfma_f32_16x16x32_bf16(
                    a[mi], bb[ni], acc[mi][ni], 0, 0, 0);
    }

    unsigned short* yb = yT + (size_t)b * DOUT * NN;
    #pragma unroll
    for (int mi = 0; mi < 4; ++mi)
        #pragma unroll
        for (int ni = 0; ni < 4; ++ni)
            #pragma unroll
            for (int r = 0; r < 4; ++r) {
                int row = m0 + wr + mi * 16 + fq * 4 + r;   // dout
                int col = n0 + wc + ni * 16 + fr;           // node
                yb[(size_t)row * NN + col] = f2bf(acc[mi][ni][r]);
            }
}

// ---------------- K5: big GEMM (R9 structure, best measured) + 1/Z epilogue ----
// C[4096 x 8192] = P[4096 x 4096] @ Y[4096 x 8192], Y^T = yT flat [8192][4096].
// out[b][node][dout] = relu(C[node][b*256+dout] / Z[node] + bias[dout]).
// LDS per buffer: [ks-half][256 rows][64B] for A and B (16KB half-tiles).
// Per tile: 4 phases (16 MFMA each), ds_reads 8/4/8/4, 2 stage-loads/phase,
// counted vmcnt(8) at both half-tile boundaries. Swizzle: chunk ^= (row>>1)&3.
__global__ __launch_bounds__(512, 2) void k_gcn(const unsigned short* __restrict__ adj,
                                                const unsigned short* __restrict__ yT,
                                                const float* __restrict__ bias,
                                                const float* __restrict__ Z,
                                                float* __restrict__ out) {
    __shared__ __align__(16) char smem[131072];   // 2 bufs x (A 32K + B 32K)

    const int tid  = threadIdx.x;
    const int lane = tid & 63, wid = tid >> 6;    // 8 waves
    const int fr = lane & 15, fq = lane >> 4;
    const int wr = wid >> 2, wc = wid & 3;        // 2 M-waves x 4 N-waves
    const int m0 = blockIdx.x * 256;              // node tile base
    const int by = blockIdx.y;                    // batch

    const char* Apanel = (const char*)(adj + (size_t)m0 * NN);          // row stride 8192 B
    const char* Bpanel = (const char*)(yT + (size_t)by * DOUT * NN);    // rows = dout 0..255

    // stage one 16KB K-half (256 rows x 32k bf16) as 2 gload_lds calls; linear LDS
    // dest, source chunk pre-swizzled with the read-side involution c ^= (r>>1)&3
    #define STAGE_HALF(gpan, ktb, KS, ldsb)                                      \
        { _Pragma("unroll")                                                      \
          for (int h = 0; h < 2; ++h) {                                          \
              int r = h * 128 + wid * 16 + (lane >> 2);                          \
              int gcol = (((lane & 3) ^ ((r >> 1) & 3)) << 4);                   \
              GLDS16((gpan) + (size_t)r * 8192 + (ktb) + (KS) * 64 + gcol,       \
                     (ldsb) + (KS) * 16384 + h * 8192 + wid * 1024);             \
          } }

    // prologue: t0 both halves + t1 ks0 (12 loads, FIFO matches steady state)
    STAGE_HALF(Apanel, 0,   0, smem);
    STAGE_HALF(Bpanel, 0,   0, smem + 32768);
    STAGE_HALF(Apanel, 0,   1, smem);
    STAGE_HALF(Bpanel, 0,   1, smem + 32768);
    STAGE_HALF(Apanel, 128, 0, smem + 65536);
    STAGE_HALF(Bpanel, 128, 0, smem + 65536 + 32768);

    f32x4 acc[8][4];
    #pragma unroll
    for (int i = 0; i < 8; ++i)
        #pragma unroll
        for (int j = 0; j < 4; ++j) acc[i][j] = (f32x4){0.f, 0.f, 0.f, 0.f};

    // per-lane read bases: logical (row, chunk fq) -> L = KS*16384 + row*64 +
    // ((fq ^ ((row>>1)&3))<<4); (row>>1)&3 == (fr>>1)&3 since rowbase%8==0
    const int chunksw = ((fq ^ ((fr >> 1) & 3)) << 4);
    const int arow = (wr * 128 + fr) * 64 + chunksw;   // + rb*1024 + KS*16384
    const int brow = (wc * 64  + fr) * 64 + chunksw;   // + ni*1024 + KS*16384

    #define READ_A(dst, RB0, KS)                                                 \
        _Pragma("unroll")                                                        \
        for (int mi = 0; mi < 4; ++mi)                                           \
            dst[mi] = *(const bf16x8*)(bufA + (KS) * 16384 + arow + ((RB0) + mi) * 1024);
    #define READ_B(dst, KS)                                                      \
        _Pragma("unroll")                                                        \
        for (int ni = 0; ni < 4; ++ni)                                           \
            dst[ni] = *(const bf16x8*)(bufB + (KS) * 16384 + brow + ni * 1024);
    #define MFMA16(AOFF, Aset, Bset)                                             \
        __builtin_amdgcn_s_setprio(1);                                           \
        _Pragma("unroll")                                                        \
        for (int mi = 0; mi < 4; ++mi)                                           \
            _Pragma("unroll")                                                    \
            for (int ni = 0; ni < 4; ++ni)                                       \
                acc[(AOFF) + mi][ni] = __builtin_amdgcn_mfma_f32_16x16x32_bf16(  \
                    Aset[mi], Bset[ni], acc[(AOFF) + mi][ni], 0, 0, 0);          \
        __builtin_amdgcn_s_setprio(0);

    asm volatile("s_waitcnt vmcnt(8)" ::: "memory");   // t0 ks0 landed
    asm volatile("s_barrier" ::: "memory");

    for (int t = 0; t < 64; ++t) {
        char* bufA  = smem + (t & 1) * 65536;
        char* bufB  = bufA + 32768;
        char* nbufA = smem + ((t + 1) & 1) * 65536;
        char* nbufB = nbufA + 32768;
        bf16x8 Af[4], Bf[4];

        // ---- Ph0: reads A(rb0-3) + B (ks0); stage (t+1) A-ks1
        READ_B(Bf, 0);
        READ_A(Af, 0, 0);
        if (t + 1 < 64) STAGE_HALF(Apanel, (t + 1) * 128, 1, nbufA);
        asm volatile("s_barrier" ::: "memory");
        asm volatile("s_waitcnt lgkmcnt(0)" ::: "memory");
        __builtin_amdgcn_sched_barrier(0);
        MFMA16(0, Af, Bf);
        asm volatile("s_barrier" ::: "memory");

        // ---- Ph1: reads A(rb4-7) ks0; stage (t+1) B-ks1
        READ_A(Af, 4, 0);
        if (t + 1 < 64) STAGE_HALF(Bpanel, (t + 1) * 128, 1, nbufB);
        asm volatile("s_barrier" ::: "memory");
        asm volatile("s_waitcnt lgkmcnt(0)" ::: "memory");
        __builtin_amdgcn_sched_barrier(0);
        MFMA16(4, Af, Bf);
        if (t < 63) { asm volatile("s_waitcnt vmcnt(8)" ::: "memory"); }  // t ks1 landed
        else        { asm volatile("s_waitcnt vmcnt(0)" ::: "memory"); }
        asm volatile("s_barrier" ::: "memory");

        // ---- Ph2: reads A(rb0-3) + B (ks1); stage (t+2) A-ks0 (ks0 reads drained)
        READ_B(Bf, 1);
        READ_A(Af, 0, 1);
        if (t + 2 < 64) STAGE_HALF(Apanel, (t + 2) * 128, 0, bufA);
        asm volatile("s_barrier" ::: "memory");
        asm volatile("s_waitcnt lgkmcnt(0)" ::: "memory");
        __builtin_amdgcn_sched_barrier(0);
        MFMA16(0, Af, Bf);
        asm volatile("s_barrier" ::: "memory");

        // ---- Ph3: reads A(rb4-7) ks1; stage (t+2) B-ks0
        READ_A(Af, 4, 1);
        if (t + 2 < 64) STAGE_HALF(Bpanel, (t + 2) * 128, 0, bufB);
        asm volatile("s_barrier" ::: "memory");
        asm volatile("s_waitcnt lgkmcnt(0)" ::: "memory");
        __builtin_amdgcn_sched_barrier(0);
        MFMA16(4, Af, Bf);
        if (t < 62)       { asm volatile("s_waitcnt vmcnt(8)" ::: "memory"); }  // (t+1) ks0 landed
        else if (t == 62) { asm volatile("s_waitcnt vmcnt(4)" ::: "memory"); }
        asm volatile("s_barrier" ::: "memory");
    }

    // ---- epilogue: scale by 1/Z[node], + bias, relu, scatter to out ----
    float bv[4];
    #pragma unroll
    for (int ni = 0; ni < 4; ++ni) bv[ni] = bias[wc * 64 + ni * 16 + fr];

    #pragma unroll
    for (int am = 0; am < 8; ++am) {
        const int node = m0 + wr * 128 + am * 16 + fq * 4;
        float4 zq = *(const float4*)&Z[node];
        float iz[4] = {1.0f / zq.x, 1.0f / zq.y, 1.0f / zq.z, 1.0f / zq.w};
        #pragma unroll
        for (int ni = 0; ni < 4; ++ni) {
            const int dcol = wc * 64 + ni * 16 + fr;
            #pragma unroll
            for (int rr = 0; rr < 4; ++rr) {
                float vv = acc[am][ni][rr] * iz[rr] + bv[ni];
                out[((size_t)by * NN + node + rr) * DOUT + dcol] = fmaxf(vv, 0.f);
            }
        }
    }
    #undef STAGE_HALF
    #undef READ_A
    #undef READ_B
    #undef MFMA16
}

extern "C" void kernel_launch(void* const* d_in, const int* in_sizes, int n_in,
                              void* d_out, int out_size, void* d_ws, size_t ws_size,
                              hipStream_t stream) {
    const float* x    = (const float*)d_in[0];
    const int*   ids  = (const int*)d_in[1];
    const float* emb  = (const float*)d_in[2];
    const float* W    = (const float*)d_in[3];
    const float* bias = (const float*)d_in[4];
    float* out = (float*)d_out;

    // workspace layout (97.1 MiB total, unchanged footprint)
    char* ws = (char*)d_ws;
    unsigned short* Pbf = (unsigned short*)ws;                            // 32 MiB
    unsigned short* Ebf = (unsigned short*)(ws + 33554432);               // 512 KiB
    float*          Z   = (float*)(ws + 33554432 + 524288);               // 16 KiB
    unsigned short* WT  = (unsigned short*)(ws + 33554432 + 1048576);     // 128 KiB
    unsigned short* yT  = (unsigned short*)(ws + 33554432 + 1048576 + 131072); // 64 MiB

    k_gather <<<NN, ED, 0, stream>>>(emb, ids, Ebf, Z);
    k_logits <<<dim3(NN / 64, NN / 64), 256, 0, stream>>>(Ebf, Pbf, Z);
    k_wt     <<<DOUT, DIN, 0, stream>>>(W, WT);
    k_y      <<<dim3(DOUT / 128, NN / 128, NB), 256, 0, stream>>>(WT, x, yT);
    k_gcn    <<<dim3(16, 32), 512, 0, stream>>>(Pbf, yT, bias, Z, out);
}